// Round 13
// baseline (99.409 us; speedup 1.0000x reference)
//
#include <hip/hip_runtime.h>
#include <cstdint>

// Lukasiewicz max-plus matmul: y[n,o] = max(b[o], max(0, max_i(x[n,i]+a[o,i]-1)))
// N=2048, K=512, OUT=512, fp32.
//
// R13 = R12 resubmitted verbatim (R12 hit a GPU-acquisition timeout; never ran).
//
// R12 theory: 2nd __launch_bounds__ arg correlates with sandbagged VGPR
// allocation (R5 (256,4)->48, R9/R10 (..,4)->60-64, R11 (256,2)->spill-
// suspect) while plain (256) gave 104-108 (R1/R2). R11's live set (~80 regs)
// exceeded the cap -> scratch spill -> flat 40us. Also: A re-laid out 64B-
// contiguous per lane (4 loads = 1 vaddr + imm offsets 0/16/32/48, one 4KB
// wave txn) and loaded NONTEMPORAL so the A stream doesn't evict the hot
// 16KB X slab from L1.
//
// Structure (from R11): 256 thr / 4 waves, 8 rows x 256 cols (4 cols/lane ->
// DS broadcast 8.2k cyc/CU, subcritical vs 16.4k VALU/SIMD floor), 4-way
// k-split (wave w owns k4 in [32w,32w+32), duplicate-free), X slab 16KB LDS
// broadcast ds_read_b128, A per-lane dbuf, merge via 32KB LDS pass (static
// indices, rule #20), grid (2,256) = 512 blocks = 2 blk/CU.

#define NROW 2048
#define NK   512
#define NCOL 512
#define RPB  8                    // rows per block
#define CBL  256                  // cols per block (4 per lane)
#define KQ   32                   // k4-steps per wave (128 / 4 waves)
typedef float f32x4 __attribute__((ext_vector_type(4)));

__device__ __forceinline__ void async_load16(const float* g, float* l) {
  __builtin_amdgcn_global_load_lds(
      (const __attribute__((address_space(1))) void*)g,
      (__attribute__((address_space(3))) void*)l, 16, 0, 0);
}

// ---- prep: Apc[(cb*128 + k4)*256 + l*4 + c] = A[cb*256 + c*64 + l][4k4..] --
// Per-lane 64B-contiguous: lane l's 4 cols sit at +0/16/32/48 bytes.
__global__ __launch_bounds__(256) void luka_prep(const float* __restrict__ A,
                                                 f32x4* __restrict__ Apc) {
  int idx = blockIdx.x * 256 + threadIdx.x;   // 512 cols * 128 k4
  int o  = idx >> 7;                          // source col
  int k4 = idx & 127;
  int cb = o >> 8, oc = o & 255;
  int c  = oc >> 6, l = oc & 63;
  f32x4 v = *(const f32x4*)(A + o * NK + k4 * 4);      // coalesced read
  Apc[((cb * 128 + k4) << 8) + (l << 2) + c] = v;      // 1MB one-shot
}

// ---- main -----------------------------------------------------------------
__global__ __launch_bounds__(256) void luka_main(
    const f32x4* __restrict__ Apc, const float* __restrict__ X,
    const float* __restrict__ Bv, float* __restrict__ Y) {
  __shared__ float xsl[RPB * NK];        // 16KB X slab
  __shared__ float red[4 * RPB * CBL];   // 32KB merge buffer (48KB total)
  const int tid  = threadIdx.x;
  const int lane = tid & 63;
  const int w    = tid >> 6;             // wave id = K-quarter (0..3)
  const int colblk  = blockIdx.x;        // 0..1
  const int rowBase = blockIdx.y * RPB;

  // Stage X[rowBase..+8)[0..512) -> xsl row-major [8][512]; 1024 f32x4 by
  // 256 threads in 4 rounds; per-wave LDS dest linear (base + lane*16) ✓.
  {
    const float* Xg = X + (size_t)rowBase * NK;
#pragma unroll
    for (int rnd = 0; rnd < 4; ++rnd) {
      int base = rnd * 256 + w * 64;     // f32x4 index, wave-uniform
      async_load16(Xg + (size_t)(base + lane) * 4, &xsl[base * 4]);
    }
  }

  // Wave's A stream: 64B/lane contiguous; 4 cols at imm offsets 0/16/32/48.
  const f32x4* __restrict__ Aw =
      Apc + (((size_t)(colblk * 128 + w * KQ)) << 8) + (lane << 2);

  float acc[RPB][4];
#pragma unroll
  for (int r = 0; r < RPB; ++r)
#pragma unroll
    for (int c = 0; c < 4; ++c) acc[r][c] = 0.0f;   // exact: ref clamps at 0

  // prime A double-buffer (nontemporal: don't evict the X slab from L1)
  f32x4 a0 = __builtin_nontemporal_load(Aw + 0);
  f32x4 a1 = __builtin_nontemporal_load(Aw + 1);
  f32x4 a2 = __builtin_nontemporal_load(Aw + 2);
  f32x4 a3 = __builtin_nontemporal_load(Aw + 3);

  __syncthreads();                       // staged X visible (vmcnt drain)

#pragma unroll 2
  for (int j = 0; j < KQ; ++j) {
    f32x4 n0, n1, n2, n3;
    if (j + 1 < KQ) {                    // 1-deep prefetch (static names)
      const f32x4* p = Aw + ((j + 1) << 8);
      n0 = __builtin_nontemporal_load(p + 0);
      n1 = __builtin_nontemporal_load(p + 1);
      n2 = __builtin_nontemporal_load(p + 2);
      n3 = __builtin_nontemporal_load(p + 3);
    }
    const int kb = (w * KQ + j) * 4;     // float col within x row
#pragma unroll
    for (int r = 0; r < RPB; ++r) {
      // one broadcast ds_read_b128 amortized over 4 cols
      const f32x4 xv = *(const f32x4*)&xsl[r * NK + kb];
      f32x4 s0 = a0 + xv;                // v_pk_add_f32 candidates
      f32x4 s1 = a1 + xv;
      f32x4 s2 = a2 + xv;
      f32x4 s3 = a3 + xv;
      acc[r][0] = fmaxf(fmaxf(s0.x, s0.y), acc[r][0]);  // v_max3
      acc[r][0] = fmaxf(fmaxf(s0.z, s0.w), acc[r][0]);
      acc[r][1] = fmaxf(fmaxf(s1.x, s1.y), acc[r][1]);
      acc[r][1] = fmaxf(fmaxf(s1.z, s1.w), acc[r][1]);
      acc[r][2] = fmaxf(fmaxf(s2.x, s2.y), acc[r][2]);
      acc[r][2] = fmaxf(fmaxf(s2.z, s2.w), acc[r][2]);
      acc[r][3] = fmaxf(fmaxf(s3.x, s3.y), acc[r][3]);
      acc[r][3] = fmaxf(fmaxf(s3.z, s3.w), acc[r][3]);
    }
    a0 = n0; a1 = n1; a2 = n2; a3 = n3;
  }

  // 4-way K-merge via red[4][8][256] (32KB), single pass, static indices.
#pragma unroll
  for (int r = 0; r < RPB; ++r)
#pragma unroll
    for (int c = 0; c < 4; ++c)
      red[(w * RPB + r) * CBL + c * 64 + lane] = acc[r][c];
  __syncthreads();

  const float bv = Bv[colblk * CBL + tid];
#pragma unroll
  for (int p = 0; p < RPB; ++p) {        // 2048 outputs / 256 thr = 8 each
    float m = fmaxf(fmaxf(red[(0 * RPB + p) * CBL + tid],
                          red[(1 * RPB + p) * CBL + tid]),
                    fmaxf(red[(2 * RPB + p) * CBL + tid],
                          red[(3 * RPB + p) * CBL + tid]));
    float t = m - 1.0f;                  // defer of -1 is exact (monotone)
    Y[(size_t)(rowBase + p) * NCOL + colblk * CBL + tid] =
        fmaxf(fmaxf(t, bv), 0.0f);       // v_max3
  }
}

// ---- fallback (R1 kernel, used only if d_ws < 1MB) ------------------------
#define TILE 64
#define BK   64
__global__ __launch_bounds__(256) void luka_fb(
    const float* __restrict__ X, const float* __restrict__ A,
    const float* __restrict__ Bv, float* __restrict__ Y) {
  __shared__ float xs[2][TILE * BK];
  __shared__ float as[2][TILE * BK];
  const int tid = threadIdx.x, wave = tid >> 6, tx = tid & 15, ty = tid >> 4;
  const int rowBase = blockIdx.y * TILE, colBase = blockIdx.x * TILE;
  uint32_t xoff[4], aoff[4];
#pragma unroll
  for (int r = 0; r < 4; ++r) {
    int row = ty * 4 + r;
    xoff[r] = (uint32_t)row * 256u + ((uint32_t)((row & 15) ^ (row >> 2)) << 4);
  }
#pragma unroll
  for (int c = 0; c < 4; ++c) {
    int row = tx * 4 + c;
    aoff[c] = (uint32_t)row * 256u + ((uint32_t)((row & 15) ^ (row >> 2)) << 4);
  }
  float acc[4][4];
#pragma unroll
  for (int r = 0; r < 4; ++r)
#pragma unroll
    for (int c = 0; c < 4; ++c) acc[r][c] = 0.0f;
  const int row0 = tid >> 4, sl = tid & 15;
  auto stage = [&](int buf, int kt) {
#pragma unroll
    for (int j = 0; j < 4; ++j) {
      int row = row0 + j * 16;
      int m = (row & 15) ^ (row >> 2);
      int kk = ((sl ^ m) << 2);
      async_load16(X + (size_t)(rowBase + row) * NK + kt * BK + kk,
                   &xs[buf][j * 1024 + wave * 256]);
      async_load16(A + (size_t)(colBase + row) * NK + kt * BK + kk,
                   &as[buf][j * 1024 + wave * 256]);
    }
  };
  stage(0, 0);
  __syncthreads();
  int buf = 0;
#pragma unroll 1
  for (int kt = 0; kt < NK / BK; ++kt) {
    if (kt < NK / BK - 1) stage(buf ^ 1, kt + 1);
    const char* xb = (const char*)&xs[buf][0];
    const char* ab = (const char*)&as[buf][0];
#pragma unroll
    for (int s4 = 0; s4 < BK / 4; ++s4) {
      f32x4 xf[4], af[4];
#pragma unroll
      for (int r = 0; r < 4; ++r)
        xf[r] = *(const f32x4*)(xb + (xoff[r] ^ (uint32_t)(s4 << 4)));
#pragma unroll
      for (int c = 0; c < 4; ++c)
        af[c] = *(const f32x4*)(ab + (aoff[c] ^ (uint32_t)(s4 << 4)));
#pragma unroll
      for (int r = 0; r < 4; ++r)
#pragma unroll
        for (int c = 0; c < 4; ++c) {
          f32x4 s = xf[r] + af[c];
          float t0 = fmaxf(fmaxf(s.x, s.y), acc[r][c]);
          acc[r][c] = fmaxf(fmaxf(s.z, s.w), t0);
        }
    }
    __syncthreads();
    buf ^= 1;
  }
  const f32x4 bv = *(const f32x4*)&Bv[colBase + tx * 4];
  float bvv[4] = {bv.x, bv.y, bv.z, bv.w};
#pragma unroll
  for (int r = 0; r < 4; ++r) {
    f32x4 o;
    o.x = fmaxf(fmaxf(acc[r][0] - 1.0f, bvv[0]), 0.0f);
    o.y = fmaxf(fmaxf(acc[r][1] - 1.0f, bvv[1]), 0.0f);
    o.z = fmaxf(fmaxf(acc[r][2] - 1.0f, bvv[2]), 0.0f);
    o.w = fmaxf(fmaxf(acc[r][3] - 1.0f, bvv[3]), 0.0f);
    *(f32x4*)&Y[(size_t)(rowBase + ty * 4 + r) * NCOL + colBase + tx * 4] = o;
  }
}

extern "C" void kernel_launch(void* const* d_in, const int* in_sizes, int n_in,
                              void* d_out, int out_size, void* d_ws, size_t ws_size,
                              hipStream_t stream) {
  const float* X = (const float*)d_in[0];   // [2048][512]
  const float* A = (const float*)d_in[1];   // [512][512]
  const float* B = (const float*)d_in[2];   // [512]
  float* Y = (float*)d_out;                 // [2048][512]

  if (ws_size >= (size_t)NCOL * NK * sizeof(float)) {
    f32x4* Apc = (f32x4*)d_ws;
    luka_prep<<<dim3(NCOL * NK / 4 / 256), dim3(256), 0, stream>>>(A, Apc);
    dim3 grid(NCOL / CBL, NROW / RPB);      // (2, 256) = 512 blocks, 2/CU
    luka_main<<<grid, dim3(256), 0, stream>>>(Apc, X, B, Y);
  } else {
    dim3 grid(NCOL / TILE, NROW / TILE);    // fallback: R1 kernel
    luka_fb<<<grid, dim3(256), 0, stream>>>(X, A, B, Y);
  }
}